// Round 3
// baseline (392.700 us; speedup 1.0000x reference)
//
#include <hip/hip_runtime.h>

#define N_NODES 100000
#define N_EDGES 1600000
#define IN_F 512
#define HID 64
#define N_CLS 32
#define NBKT 6250   // 16 nodes per bucket, exact: 6250*16 = 100000

typedef __attribute__((ext_vector_type(8))) short short8;
typedef __attribute__((ext_vector_type(4))) float f32x4;

__device__ __forceinline__ unsigned short f2bf(float f) {
  unsigned int u = __float_as_uint(f);
  u += 0x7FFFu + ((u >> 16) & 1u);
  return (unsigned short)(u >> 16);
}
__device__ __forceinline__ float bf2f(unsigned int s) {
  return __uint_as_float(s << 16);
}

// ---------- CSR build ----------
__global__ __launch_bounds__(256) void hist_k(const int* __restrict__ ei, int* __restrict__ cnt) {
  int e = blockIdx.x * 256 + threadIdx.x;
  if (e < N_EDGES) atomicAdd(&cnt[ei[N_EDGES + e]], 1);
}

__global__ __launch_bounds__(256) void scan_blocks_k(const int* __restrict__ cnt,
                                                     int* __restrict__ incl,
                                                     int* __restrict__ aux) {
  __shared__ int wsum[4];
  int tid = threadIdx.x;
  int lane = tid & 63, wid = tid >> 6;
  int i0 = blockIdx.x * 1024 + tid * 4;
  int4 v = make_int4(0, 0, 0, 0);
  if (i0 + 3 < N_NODES) v = *(const int4*)(cnt + i0);
  else {
    if (i0 < N_NODES)     v.x = cnt[i0];
    if (i0 + 1 < N_NODES) v.y = cnt[i0 + 1];
    if (i0 + 2 < N_NODES) v.z = cnt[i0 + 2];
  }
  int s1 = v.x, s2 = s1 + v.y, s3 = s2 + v.z, s4 = s3 + v.w;
  int s = s4;
  for (int off = 1; off < 64; off <<= 1) { int t = __shfl_up(s, off); if (lane >= off) s += t; }
  if (lane == 63) wsum[wid] = s;
  __syncthreads();
  int wpre = 0;
  for (int w = 0; w < wid; ++w) wpre += wsum[w];
  int pre = wpre + s - s4;
  if (i0 < N_NODES)     incl[i0]     = pre + s1;
  if (i0 + 1 < N_NODES) incl[i0 + 1] = pre + s2;
  if (i0 + 2 < N_NODES) incl[i0 + 2] = pre + s3;
  if (i0 + 3 < N_NODES) incl[i0 + 3] = pre + s4;
  if (tid == 255) aux[blockIdx.x] = wpre + s;
}

__global__ __launch_bounds__(128) void scan_aux_k(int* aux, int nb) {
  __shared__ int w0s;
  int tid = threadIdx.x, lane = tid & 63, wid = tid >> 6;
  int v = (tid < nb) ? aux[tid] : 0;
  int s = v;
  for (int off = 1; off < 64; off <<= 1) { int t = __shfl_up(s, off); if (lane >= off) s += t; }
  if (tid == 63) w0s = s;
  __syncthreads();
  int incl = s + (wid ? w0s : 0);
  if (tid < nb) aux[tid] = incl - v;
}

// rowptr finalize + per-bucket cursor seed + dinv
__global__ __launch_bounds__(256) void finalize_k(const int* __restrict__ cnt,
                                                  int* __restrict__ rowptr,
                                                  const int* __restrict__ aux,
                                                  int* __restrict__ bcur,
                                                  float* __restrict__ dinv) {
  int i = blockIdx.x * 256 + threadIdx.x;
  if (i == 0) { rowptr[0] = 0; bcur[0] = 0; }
  if (i < N_NODES) {
    int r = rowptr[i + 1] + aux[i >> 10];
    rowptr[i + 1] = r;
    if (((i + 1) & 15) == 0) bcur[(i + 1) >> 4] = r;   // bucket (i+1)/16 start
    dinv[i] = rsqrtf((float)(cnt[i] + 1));
  }
}

// pass A: scatter edges into 16-node buckets (packed src<<4 | dst&15)
__global__ __launch_bounds__(256) void passA_k(const int* __restrict__ ei,
                                               int* __restrict__ bcur,
                                               unsigned* __restrict__ tmp) {
  int e = blockIdx.x * 256 + threadIdx.x;
  if (e < N_EDGES) {
    int s = ei[e], d = ei[N_EDGES + e];
    int p = atomicAdd(&bcur[d >> 4], 1);
    tmp[p] = ((unsigned)s << 4) | (unsigned)(d & 15);
  }
}

// pass B: within-bucket scatter to exact per-node positions
__global__ __launch_bounds__(256) void passB_k(const unsigned* __restrict__ tmp,
                                               const int* __restrict__ rowptr,
                                               int* __restrict__ srcs) {
  __shared__ int cur[16];
  int b = blockIdx.x;
  int tid = threadIdx.x;
  int base = rowptr[b * 16];
  int end  = rowptr[b * 16 + 16];
  if (tid < 16) cur[tid] = rowptr[b * 16 + tid];
  __syncthreads();
  for (int i = base + tid; i < end; i += 256) {
    unsigned v = tmp[i];
    int p = atomicAdd(&cur[v & 15u], 1);
    srcs[p] = (int)(v >> 4);
  }
}

// ---------- W1 transpose to bf16 ----------
__global__ __launch_bounds__(256) void w1t_k(const float* __restrict__ W1,
                                             unsigned short* __restrict__ W1t) {
  int i = blockIdx.x * 256 + threadIdx.x;
  if (i < IN_F * HID) {
    int n = i >> 9, k = i & 511;
    W1t[i] = f2bf(W1[(size_t)k * HID + n]);
  }
}

// ---------- GEMM1 (MFMA bf16): h0s = dinv * (x @ W1), bf16 ----------
__global__ __launch_bounds__(256) void gemm1_mfma_k(const float* __restrict__ x,
                                                    const unsigned short* __restrict__ W1t,
                                                    const float* __restrict__ dinv,
                                                    unsigned short* __restrict__ h0s) {
  __shared__ __align__(16) char As[64 * 128];
  __shared__ __align__(16) char Ws[64 * 128];
  int tid = threadIdx.x;
  int wave = tid >> 6, lane = tid & 63;
  int row0 = blockIdx.x * 64;
  f32x4 acc[4] = {{0.f,0.f,0.f,0.f},{0.f,0.f,0.f,0.f},{0.f,0.f,0.f,0.f},{0.f,0.f,0.f,0.f}};

  int l15 = lane & 15, lhi = lane >> 4;
  int rA = (wave << 4) + l15;

  for (int k0 = 0; k0 < IN_F; k0 += 64) {
    #pragma unroll
    for (int i = 0; i < 4; ++i) {
      int f = tid + i * 256;
      int r = f >> 4, c4 = (f & 15) << 2;
      float4 v = make_float4(0.f, 0.f, 0.f, 0.f);
      int gr = row0 + r;
      if (gr < N_NODES) v = *(const float4*)(x + (size_t)gr * IN_F + k0 + c4);
      ushort4 u;
      u.x = f2bf(v.x); u.y = f2bf(v.y); u.z = f2bf(v.z); u.w = f2bf(v.w);
      int byte = r * 128 + (c4 << 1);
      byte ^= (r & 7) << 4;
      *(ushort4*)(As + byte) = u;
    }
    #pragma unroll
    for (int i = 0; i < 2; ++i) {
      int f = tid + i * 256;
      int n = f >> 3, k8 = (f & 7) << 3;
      uint4 v = *(const uint4*)(W1t + (size_t)n * IN_F + k0 + k8);
      int byte = n * 128 + (k8 << 1);
      byte ^= (n & 7) << 4;
      *(uint4*)(Ws + byte) = v;
    }
    __syncthreads();
    #pragma unroll
    for (int ks = 0; ks < 64; ks += 32) {
      int kk = ks + (lhi << 3);
      int ba = rA * 128 + (kk << 1); ba ^= (rA & 7) << 4;
      short8 a = *(const short8*)(As + ba);
      #pragma unroll
      for (int j = 0; j < 4; ++j) {
        int nB = (j << 4) + l15;
        int bb = nB * 128 + (kk << 1); bb ^= (nB & 7) << 4;
        short8 b = *(const short8*)(Ws + bb);
        acc[j] = __builtin_amdgcn_mfma_f32_16x16x32_bf16(a, b, acc[j], 0, 0, 0);
      }
    }
    __syncthreads();
  }
  int rbase = row0 + (wave << 4) + (lhi << 2);
  #pragma unroll
  for (int r = 0; r < 4; ++r) {
    int gr = rbase + r;
    if (gr < N_NODES) {
      float dn = dinv[gr];
      #pragma unroll
      for (int j = 0; j < 4; ++j)
        h0s[(size_t)gr * HID + (j << 4) + l15] = f2bf(dn * acc[j][r]);
    }
  }
}

// ---------- agg1: one wave/node, 2-way edge split, 2 features per lane ----------
__global__ __launch_bounds__(256) void agg1_k(const unsigned* __restrict__ h0u,
                                              const int* __restrict__ rowptr,
                                              const int* __restrict__ srcs,
                                              const float* __restrict__ dinv,
                                              const float* __restrict__ b1,
                                              float* __restrict__ out) {
  int idx = blockIdx.x * 256 + threadIdx.x;
  int node = idx >> 6;
  if (node >= N_NODES) return;
  int lane = threadIdx.x & 63;
  int fl = lane & 31, half = lane >> 5;
  int p0 = rowptr[node], p1 = rowptr[node + 1];
  int c = p1 - p0;
  int ps = p0 + ((c * half) >> 1);
  int pe = p0 + ((c * (half + 1)) >> 1);
  float ax = 0.f, ay = 0.f;
  if (!half) {
    unsigned u = h0u[(size_t)node * 32 + fl];   // self (pre-scaled)
    ax = bf2f(u & 0xffffu); ay = bf2f(u >> 16);
  }
  int p = ps;
  for (; p + 4 <= pe; p += 4) {
    int s0 = srcs[p], s1 = srcs[p + 1], s2 = srcs[p + 2], s3 = srcs[p + 3];
    unsigned u0 = h0u[(size_t)s0 * 32 + fl];
    unsigned u1 = h0u[(size_t)s1 * 32 + fl];
    unsigned u2 = h0u[(size_t)s2 * 32 + fl];
    unsigned u3 = h0u[(size_t)s3 * 32 + fl];
    ax += (bf2f(u0 & 0xffffu) + bf2f(u1 & 0xffffu)) + (bf2f(u2 & 0xffffu) + bf2f(u3 & 0xffffu));
    ay += (bf2f(u0 >> 16) + bf2f(u1 >> 16)) + (bf2f(u2 >> 16) + bf2f(u3 >> 16));
  }
  for (; p < pe; ++p) {
    unsigned u = h0u[(size_t)srcs[p] * 32 + fl];
    ax += bf2f(u & 0xffffu); ay += bf2f(u >> 16);
  }
  ax += __shfl_xor(ax, 32);
  ay += __shfl_xor(ay, 32);
  if (!half) {
    float dn = dinv[node];
    float2 st;
    st.x = fmaxf(dn * ax + b1[2 * fl], 0.f);
    st.y = fmaxf(dn * ay + b1[2 * fl + 1], 0.f);
    *(float2*)(out + (size_t)node * HID + 2 * fl) = st;
  }
}

// ---------- GEMM2: h2b = bf16(dinv * (h @ W2)) ----------
__global__ __launch_bounds__(256) void gemm2_k(const float* __restrict__ h,
                                               const float* __restrict__ W2,
                                               const float* __restrict__ dinv,
                                               unsigned short* __restrict__ h2b) {
  __shared__ float w2s[HID * N_CLS];
  __shared__ float hs[8][HID];
  int tid = threadIdx.x;
  for (int i = tid; i < HID * N_CLS; i += 256) w2s[i] = W2[i];
  int node0 = blockIdx.x * 8;
  for (int i = tid; i < 8 * HID; i += 256) {
    int r = i >> 6, c = i & 63;
    int g = node0 + r;
    hs[r][c] = (g < N_NODES) ? h[(size_t)g * HID + c] : 0.f;
  }
  __syncthreads();
  int nl = tid >> 5, cls = tid & 31;
  float acc = 0.f;
  #pragma unroll
  for (int k = 0; k < HID; ++k) acc += hs[nl][k] * w2s[k * N_CLS + cls];
  int g = node0 + nl;
  if (g < N_NODES) h2b[(size_t)g * N_CLS + cls] = f2bf(dinv[g] * acc);
}

// ---------- agg2: one wave/node, 4-way edge split, 2 features per lane ----------
__global__ __launch_bounds__(256) void agg2_k(const unsigned* __restrict__ h2u,
                                              const int* __restrict__ rowptr,
                                              const int* __restrict__ srcs,
                                              const float* __restrict__ dinv,
                                              const float* __restrict__ b2,
                                              float* __restrict__ out) {
  int idx = blockIdx.x * 256 + threadIdx.x;
  int node = idx >> 6;
  if (node >= N_NODES) return;
  int lane = threadIdx.x & 63;
  int fl = lane & 15, g = lane >> 4;
  int p0 = rowptr[node], p1 = rowptr[node + 1];
  int c = p1 - p0;
  int ps = p0 + ((c * g) >> 2);
  int pe = p0 + ((c * (g + 1)) >> 2);
  float ax = 0.f, ay = 0.f;
  if (g == 0) {
    unsigned u = h2u[(size_t)node * 16 + fl];
    ax = bf2f(u & 0xffffu); ay = bf2f(u >> 16);
  }
  int p = ps;
  for (; p + 4 <= pe; p += 4) {
    int s0 = srcs[p], s1 = srcs[p + 1], s2 = srcs[p + 2], s3 = srcs[p + 3];
    unsigned u0 = h2u[(size_t)s0 * 16 + fl];
    unsigned u1 = h2u[(size_t)s1 * 16 + fl];
    unsigned u2 = h2u[(size_t)s2 * 16 + fl];
    unsigned u3 = h2u[(size_t)s3 * 16 + fl];
    ax += (bf2f(u0 & 0xffffu) + bf2f(u1 & 0xffffu)) + (bf2f(u2 & 0xffffu) + bf2f(u3 & 0xffffu));
    ay += (bf2f(u0 >> 16) + bf2f(u1 >> 16)) + (bf2f(u2 >> 16) + bf2f(u3 >> 16));
  }
  for (; p < pe; ++p) {
    unsigned u = h2u[(size_t)srcs[p] * 16 + fl];
    ax += bf2f(u & 0xffffu); ay += bf2f(u >> 16);
  }
  ax += __shfl_xor(ax, 32); ax += __shfl_xor(ax, 16);
  ay += __shfl_xor(ay, 32); ay += __shfl_xor(ay, 16);
  if (g == 0) {
    float dn = dinv[node];
    float2 st;
    st.x = dn * ax + b2[2 * fl];
    st.y = dn * ay + b2[2 * fl + 1];
    *(float2*)(out + (size_t)node * N_CLS + 2 * fl) = st;
  }
}

extern "C" void kernel_launch(void* const* d_in, const int* in_sizes, int n_in,
                              void* d_out, int out_size, void* d_ws, size_t ws_size,
                              hipStream_t stream) {
  const float* x  = (const float*)d_in[0];
  const int*   ei = (const int*)d_in[1];
  const float* W1 = (const float*)d_in[2];
  const float* b1 = (const float*)d_in[3];
  const float* W2 = (const float*)d_in[4];
  const float* b2 = (const float*)d_in[5];
  float* out_h = (float*)d_out;
  float* out_z = out_h + (size_t)N_NODES * HID;

  char* ws = (char*)d_ws;
  int* cnt            = (int*)(ws + 0);                       // 400 KB
  int* rowptr         = (int*)(ws + (512 << 10));             // 400 KB + 4
  float* dinv         = (float*)(ws + (1024 << 10));          // 400 KB
  int* aux            = (int*)(ws + (1440 << 10));            // <1 KB
  unsigned short* W1t = (unsigned short*)(ws + (1444 << 10)); // 64 KB
  int* bcur           = (int*)(ws + (1512 << 10));            // ~25 KB
  unsigned* tmp       = (unsigned*)(ws + (1544 << 10));       // 6.4 MB
  int* srcs           = (int*)(ws + (8ull << 20));            // 6.4 MB
  unsigned short* h0s = (unsigned short*)(ws + (15ull << 20));// 12.8 MB
  unsigned short* h2b = (unsigned short*)(ws + (28ull << 20));// 6.4 MB

  int nb = (N_NODES + 1023) / 1024;

  hipMemsetAsync(cnt, 0, N_NODES * sizeof(int), stream);
  w1t_k<<<(IN_F * HID + 255) / 256, 256, 0, stream>>>(W1, W1t);
  hist_k<<<(N_EDGES + 255) / 256, 256, 0, stream>>>(ei, cnt);
  scan_blocks_k<<<nb, 256, 0, stream>>>(cnt, rowptr + 1, aux);
  scan_aux_k<<<1, 128, 0, stream>>>(aux, nb);
  finalize_k<<<(N_NODES + 255) / 256, 256, 0, stream>>>(cnt, rowptr, aux, bcur, dinv);
  passA_k<<<(N_EDGES + 255) / 256, 256, 0, stream>>>(ei, bcur, tmp);
  passB_k<<<NBKT, 256, 0, stream>>>(tmp, rowptr, srcs);
  gemm1_mfma_k<<<(N_NODES + 63) / 64, 256, 0, stream>>>(x, W1t, dinv, h0s);
  agg1_k<<<(N_NODES * 64) / 256, 256, 0, stream>>>((const unsigned*)h0s, rowptr, srcs, dinv, b1, out_h);
  gemm2_k<<<(N_NODES + 7) / 8, 256, 0, stream>>>(out_h, W2, dinv, h2b);
  agg2_k<<<(N_NODES * 64) / 256, 256, 0, stream>>>((const unsigned*)h2b, rowptr, srcs, dinv, b2, out_z);
}

// Round 4
// 280.983 us; speedup vs baseline: 1.3976x; 1.3976x over previous
//
#include <hip/hip_runtime.h>

#define N_NODES 100000
#define N_EDGES 1600000
#define IN_F 512
#define HID 64
#define N_CLS 32
#define NBKT2 391      // 256-node buckets: ceil(100000/256)
#define EBLK 8192      // edges per passA block
#define NBLKA ((N_EDGES + EBLK - 1) / EBLK)   // 196

typedef __attribute__((ext_vector_type(8))) short short8;
typedef __attribute__((ext_vector_type(4))) float f32x4;

__device__ __forceinline__ unsigned short f2bf(float f) {
  unsigned int u = __float_as_uint(f);
  u += 0x7FFFu + ((u >> 16) & 1u);
  return (unsigned short)(u >> 16);
}
__device__ __forceinline__ float bf2f(unsigned int s) {
  return __uint_as_float(s << 16);
}

// ---------- degree histogram ----------
__global__ __launch_bounds__(256) void hist_k(const int* __restrict__ ei, int* __restrict__ cnt) {
  int e = blockIdx.x * 256 + threadIdx.x;
  if (e < N_EDGES) atomicAdd(&cnt[ei[N_EDGES + e]], 1);
}

__global__ __launch_bounds__(256) void scan_blocks_k(const int* __restrict__ cnt,
                                                     int* __restrict__ incl,
                                                     int* __restrict__ aux) {
  __shared__ int wsum[4];
  int tid = threadIdx.x;
  int lane = tid & 63, wid = tid >> 6;
  int i0 = blockIdx.x * 1024 + tid * 4;
  int4 v = make_int4(0, 0, 0, 0);
  if (i0 + 3 < N_NODES) v = *(const int4*)(cnt + i0);
  else {
    if (i0 < N_NODES)     v.x = cnt[i0];
    if (i0 + 1 < N_NODES) v.y = cnt[i0 + 1];
    if (i0 + 2 < N_NODES) v.z = cnt[i0 + 2];
  }
  int s1 = v.x, s2 = s1 + v.y, s3 = s2 + v.z, s4 = s3 + v.w;
  int s = s4;
  for (int off = 1; off < 64; off <<= 1) { int t = __shfl_up(s, off); if (lane >= off) s += t; }
  if (lane == 63) wsum[wid] = s;
  __syncthreads();
  int wpre = 0;
  for (int w = 0; w < wid; ++w) wpre += wsum[w];
  int pre = wpre + s - s4;
  if (i0 < N_NODES)     incl[i0]     = pre + s1;
  if (i0 + 1 < N_NODES) incl[i0 + 1] = pre + s2;
  if (i0 + 2 < N_NODES) incl[i0 + 2] = pre + s3;
  if (i0 + 3 < N_NODES) incl[i0 + 3] = pre + s4;
  if (tid == 255) aux[blockIdx.x] = wpre + s;
}

__global__ __launch_bounds__(128) void scan_aux_k(int* aux, int nb) {
  __shared__ int w0s;
  int tid = threadIdx.x, lane = tid & 63, wid = tid >> 6;
  int v = (tid < nb) ? aux[tid] : 0;
  int s = v;
  for (int off = 1; off < 64; off <<= 1) { int t = __shfl_up(s, off); if (lane >= off) s += t; }
  if (tid == 63) w0s = s;
  __syncthreads();
  int incl = s + (wid ? w0s : 0);
  if (tid < nb) aux[tid] = incl - v;
}

// rowptr finalize + 256-node bucket cursor seed + dinv
__global__ __launch_bounds__(256) void finalize_k(const int* __restrict__ cnt,
                                                  int* __restrict__ rowptr,
                                                  const int* __restrict__ aux,
                                                  int* __restrict__ bcur,
                                                  float* __restrict__ dinv) {
  int i = blockIdx.x * 256 + threadIdx.x;
  if (i == 0) { rowptr[0] = 0; bcur[0] = 0; }
  if (i < N_NODES) {
    int r = rowptr[i + 1] + aux[i >> 10];
    rowptr[i + 1] = r;
    if (((i + 1) & 255) == 0) bcur[(i + 1) >> 8] = r;
    dinv[i] = rsqrtf((float)(cnt[i] + 1));
  }
}

// pass A: block-private run reservation into 256-node buckets
__global__ __launch_bounds__(256) void passA_k(const int* __restrict__ ei,
                                               int* __restrict__ bcur,
                                               unsigned* __restrict__ tmp) {
  __shared__ int lhist[NBKT2];
  __shared__ int gcur[NBKT2];
  int tid = threadIdx.x;
  int e0 = blockIdx.x * EBLK;
  int e1 = min(e0 + EBLK, N_EDGES);
  for (int b = tid; b < NBKT2; b += 256) lhist[b] = 0;
  __syncthreads();
  for (int e = e0 + tid; e < e1; e += 256) {
    int d = ei[N_EDGES + e];
    atomicAdd(&lhist[d >> 8], 1);
  }
  __syncthreads();
  for (int b = tid; b < NBKT2; b += 256) {
    int c = lhist[b];
    gcur[b] = c ? atomicAdd(&bcur[b], c) : 0;
  }
  __syncthreads();
  for (int e = e0 + tid; e < e1; e += 256) {
    int s = ei[e], d = ei[N_EDGES + e];
    int p = atomicAdd(&gcur[d >> 8], 1);
    tmp[p] = ((unsigned)s << 8) | (unsigned)(d & 255);
  }
}

// pass B: within-bucket exact per-node placement (one block per bucket)
__global__ __launch_bounds__(256) void passB_k(const unsigned* __restrict__ tmp,
                                               const int* __restrict__ rowptr,
                                               int* __restrict__ srcs) {
  __shared__ int cur[256];
  int b = blockIdx.x, tid = threadIdx.x;
  int n0 = b << 8;
  int n1 = min(n0 + 256, N_NODES);
  if (n0 + tid < n1) cur[tid] = rowptr[n0 + tid];
  __syncthreads();
  int base = rowptr[n0], end = rowptr[n1];
  for (int i = base + tid; i < end; i += 256) {
    unsigned v = tmp[i];
    int p = atomicAdd(&cur[v & 255u], 1);
    srcs[p] = (int)(v >> 8);
  }
}

// ---------- W1 transpose to bf16 ----------
__global__ __launch_bounds__(256) void w1t_k(const float* __restrict__ W1,
                                             unsigned short* __restrict__ W1t) {
  int i = blockIdx.x * 256 + threadIdx.x;
  if (i < IN_F * HID) {
    int n = i >> 9, k = i & 511;
    W1t[i] = f2bf(W1[(size_t)k * HID + n]);
  }
}

// ---------- GEMM1 (MFMA bf16): h0s = dinv * (x @ W1), bf16 ----------
__global__ __launch_bounds__(256) void gemm1_mfma_k(const float* __restrict__ x,
                                                    const unsigned short* __restrict__ W1t,
                                                    const float* __restrict__ dinv,
                                                    unsigned short* __restrict__ h0s) {
  __shared__ __align__(16) char As[64 * 128];
  __shared__ __align__(16) char Ws[64 * 128];
  int tid = threadIdx.x;
  int wave = tid >> 6, lane = tid & 63;
  int row0 = blockIdx.x * 64;
  f32x4 acc[4] = {{0.f,0.f,0.f,0.f},{0.f,0.f,0.f,0.f},{0.f,0.f,0.f,0.f},{0.f,0.f,0.f,0.f}};

  int l15 = lane & 15, lhi = lane >> 4;
  int rA = (wave << 4) + l15;

  for (int k0 = 0; k0 < IN_F; k0 += 64) {
    #pragma unroll
    for (int i = 0; i < 4; ++i) {
      int f = tid + i * 256;
      int r = f >> 4, c4 = (f & 15) << 2;
      float4 v = make_float4(0.f, 0.f, 0.f, 0.f);
      int gr = row0 + r;
      if (gr < N_NODES) v = *(const float4*)(x + (size_t)gr * IN_F + k0 + c4);
      ushort4 u;
      u.x = f2bf(v.x); u.y = f2bf(v.y); u.z = f2bf(v.z); u.w = f2bf(v.w);
      int byte = r * 128 + (c4 << 1);
      byte ^= (r & 7) << 4;
      *(ushort4*)(As + byte) = u;
    }
    #pragma unroll
    for (int i = 0; i < 2; ++i) {
      int f = tid + i * 256;
      int n = f >> 3, k8 = (f & 7) << 3;
      uint4 v = *(const uint4*)(W1t + (size_t)n * IN_F + k0 + k8);
      int byte = n * 128 + (k8 << 1);
      byte ^= (n & 7) << 4;
      *(uint4*)(Ws + byte) = v;
    }
    __syncthreads();
    #pragma unroll
    for (int ks = 0; ks < 64; ks += 32) {
      int kk = ks + (lhi << 3);
      int ba = rA * 128 + (kk << 1); ba ^= (rA & 7) << 4;
      short8 a = *(const short8*)(As + ba);
      #pragma unroll
      for (int j = 0; j < 4; ++j) {
        int nB = (j << 4) + l15;
        int bb = nB * 128 + (kk << 1); bb ^= (nB & 7) << 4;
        short8 b = *(const short8*)(Ws + bb);
        acc[j] = __builtin_amdgcn_mfma_f32_16x16x32_bf16(a, b, acc[j], 0, 0, 0);
      }
    }
    __syncthreads();
  }
  int rbase = row0 + (wave << 4) + (lhi << 2);
  #pragma unroll
  for (int r = 0; r < 4; ++r) {
    int gr = rbase + r;
    if (gr < N_NODES) {
      float dn = dinv[gr];
      #pragma unroll
      for (int j = 0; j < 4; ++j)
        h0s[(size_t)gr * HID + (j << 4) + l15] = f2bf(dn * acc[j][r]);
    }
  }
}

// ---------- agg1: one wave/node, 4-way edge split, 4 features per lane (uint2) ----------
__global__ __launch_bounds__(256) void agg1_k(const uint2* __restrict__ h0u,
                                              const int* __restrict__ rowptr,
                                              const int* __restrict__ srcs,
                                              const float* __restrict__ dinv,
                                              const float* __restrict__ b1,
                                              float* __restrict__ out) {
  int idx = blockIdx.x * 256 + threadIdx.x;
  int node = idx >> 6;
  if (node >= N_NODES) return;
  int lane = threadIdx.x & 63;
  int fl = lane & 15, g = lane >> 4;
  int p0 = rowptr[node], p1 = rowptr[node + 1];
  int c = p1 - p0;
  int ps = p0 + ((c * g) >> 2);
  int pe = p0 + ((c * (g + 1)) >> 2);
  float a0 = 0.f, a1 = 0.f, a2 = 0.f, a3 = 0.f;
  if (g == 0) {
    uint2 u = h0u[(size_t)node * 16 + fl];   // self (pre-scaled)
    a0 = bf2f(u.x & 0xffffu); a1 = bf2f(u.x >> 16);
    a2 = bf2f(u.y & 0xffffu); a3 = bf2f(u.y >> 16);
  }
  int p = ps;
  for (; p + 4 <= pe; p += 4) {
    int s0 = srcs[p], s1 = srcs[p + 1], s2 = srcs[p + 2], s3 = srcs[p + 3];
    uint2 u0 = h0u[(size_t)s0 * 16 + fl];
    uint2 u1 = h0u[(size_t)s1 * 16 + fl];
    uint2 u2 = h0u[(size_t)s2 * 16 + fl];
    uint2 u3 = h0u[(size_t)s3 * 16 + fl];
    a0 += (bf2f(u0.x & 0xffffu) + bf2f(u1.x & 0xffffu)) + (bf2f(u2.x & 0xffffu) + bf2f(u3.x & 0xffffu));
    a1 += (bf2f(u0.x >> 16) + bf2f(u1.x >> 16)) + (bf2f(u2.x >> 16) + bf2f(u3.x >> 16));
    a2 += (bf2f(u0.y & 0xffffu) + bf2f(u1.y & 0xffffu)) + (bf2f(u2.y & 0xffffu) + bf2f(u3.y & 0xffffu));
    a3 += (bf2f(u0.y >> 16) + bf2f(u1.y >> 16)) + (bf2f(u2.y >> 16) + bf2f(u3.y >> 16));
  }
  for (; p < pe; ++p) {
    uint2 u = h0u[(size_t)srcs[p] * 16 + fl];
    a0 += bf2f(u.x & 0xffffu); a1 += bf2f(u.x >> 16);
    a2 += bf2f(u.y & 0xffffu); a3 += bf2f(u.y >> 16);
  }
  a0 += __shfl_xor(a0, 32); a0 += __shfl_xor(a0, 16);
  a1 += __shfl_xor(a1, 32); a1 += __shfl_xor(a1, 16);
  a2 += __shfl_xor(a2, 32); a2 += __shfl_xor(a2, 16);
  a3 += __shfl_xor(a3, 32); a3 += __shfl_xor(a3, 16);
  if (g == 0) {
    float dn = dinv[node];
    float4 st;
    st.x = fmaxf(dn * a0 + b1[4 * fl + 0], 0.f);
    st.y = fmaxf(dn * a1 + b1[4 * fl + 1], 0.f);
    st.z = fmaxf(dn * a2 + b1[4 * fl + 2], 0.f);
    st.w = fmaxf(dn * a3 + b1[4 * fl + 3], 0.f);
    *(float4*)(out + (size_t)node * HID + 4 * fl) = st;
  }
}

// ---------- GEMM2: h2b = bf16(dinv * (h @ W2)) ----------
__global__ __launch_bounds__(256) void gemm2_k(const float* __restrict__ h,
                                               const float* __restrict__ W2,
                                               const float* __restrict__ dinv,
                                               unsigned short* __restrict__ h2b) {
  __shared__ float w2s[HID * N_CLS];
  __shared__ float hs[8][HID];
  int tid = threadIdx.x;
  for (int i = tid; i < HID * N_CLS; i += 256) w2s[i] = W2[i];
  int node0 = blockIdx.x * 8;
  for (int i = tid; i < 8 * HID; i += 256) {
    int r = i >> 6, c = i & 63;
    int g = node0 + r;
    hs[r][c] = (g < N_NODES) ? h[(size_t)g * HID + c] : 0.f;
  }
  __syncthreads();
  int nl = tid >> 5, cls = tid & 31;
  float acc = 0.f;
  #pragma unroll
  for (int k = 0; k < HID; ++k) acc += hs[nl][k] * w2s[k * N_CLS + cls];
  int g = node0 + nl;
  if (g < N_NODES) h2b[(size_t)g * N_CLS + cls] = f2bf(dinv[g] * acc);
}

// ---------- agg2: one wave/node, 4-way edge split, 2 features per lane ----------
__global__ __launch_bounds__(256) void agg2_k(const unsigned* __restrict__ h2u,
                                              const int* __restrict__ rowptr,
                                              const int* __restrict__ srcs,
                                              const float* __restrict__ dinv,
                                              const float* __restrict__ b2,
                                              float* __restrict__ out) {
  int idx = blockIdx.x * 256 + threadIdx.x;
  int node = idx >> 6;
  if (node >= N_NODES) return;
  int lane = threadIdx.x & 63;
  int fl = lane & 15, g = lane >> 4;
  int p0 = rowptr[node], p1 = rowptr[node + 1];
  int c = p1 - p0;
  int ps = p0 + ((c * g) >> 2);
  int pe = p0 + ((c * (g + 1)) >> 2);
  float ax = 0.f, ay = 0.f;
  if (g == 0) {
    unsigned u = h2u[(size_t)node * 16 + fl];
    ax = bf2f(u & 0xffffu); ay = bf2f(u >> 16);
  }
  int p = ps;
  for (; p + 4 <= pe; p += 4) {
    int s0 = srcs[p], s1 = srcs[p + 1], s2 = srcs[p + 2], s3 = srcs[p + 3];
    unsigned u0 = h2u[(size_t)s0 * 16 + fl];
    unsigned u1 = h2u[(size_t)s1 * 16 + fl];
    unsigned u2 = h2u[(size_t)s2 * 16 + fl];
    unsigned u3 = h2u[(size_t)s3 * 16 + fl];
    ax += (bf2f(u0 & 0xffffu) + bf2f(u1 & 0xffffu)) + (bf2f(u2 & 0xffffu) + bf2f(u3 & 0xffffu));
    ay += (bf2f(u0 >> 16) + bf2f(u1 >> 16)) + (bf2f(u2 >> 16) + bf2f(u3 >> 16));
  }
  for (; p < pe; ++p) {
    unsigned u = h2u[(size_t)srcs[p] * 16 + fl];
    ax += bf2f(u & 0xffffu); ay += bf2f(u >> 16);
  }
  ax += __shfl_xor(ax, 32); ax += __shfl_xor(ax, 16);
  ay += __shfl_xor(ay, 32); ay += __shfl_xor(ay, 16);
  if (g == 0) {
    float dn = dinv[node];
    float2 st;
    st.x = dn * ax + b2[2 * fl];
    st.y = dn * ay + b2[2 * fl + 1];
    *(float2*)(out + (size_t)node * N_CLS + 2 * fl) = st;
  }
}

extern "C" void kernel_launch(void* const* d_in, const int* in_sizes, int n_in,
                              void* d_out, int out_size, void* d_ws, size_t ws_size,
                              hipStream_t stream) {
  const float* x  = (const float*)d_in[0];
  const int*   ei = (const int*)d_in[1];
  const float* W1 = (const float*)d_in[2];
  const float* b1 = (const float*)d_in[3];
  const float* W2 = (const float*)d_in[4];
  const float* b2 = (const float*)d_in[5];
  float* out_h = (float*)d_out;
  float* out_z = out_h + (size_t)N_NODES * HID;

  char* ws = (char*)d_ws;
  int* cnt            = (int*)(ws + 0);                       // 400 KB
  int* rowptr         = (int*)(ws + (512 << 10));             // 400 KB + 4
  float* dinv         = (float*)(ws + (1024 << 10));          // 400 KB
  int* aux            = (int*)(ws + (1440 << 10));            // <1 KB
  unsigned short* W1t = (unsigned short*)(ws + (1444 << 10)); // 64 KB
  int* bcur           = (int*)(ws + (1512 << 10));            // 1.6 KB
  unsigned* tmp       = (unsigned*)(ws + (1544 << 10));       // 6.4 MB
  int* srcs           = (int*)(ws + (8ull << 20));            // 6.4 MB
  unsigned short* h0s = (unsigned short*)(ws + (15ull << 20));// 12.8 MB
  unsigned short* h2b = (unsigned short*)(ws + (28ull << 20));// 6.4 MB

  int nb = (N_NODES + 1023) / 1024;

  hipMemsetAsync(cnt, 0, N_NODES * sizeof(int), stream);
  w1t_k<<<(IN_F * HID + 255) / 256, 256, 0, stream>>>(W1, W1t);
  hist_k<<<(N_EDGES + 255) / 256, 256, 0, stream>>>(ei, cnt);
  scan_blocks_k<<<nb, 256, 0, stream>>>(cnt, rowptr + 1, aux);
  scan_aux_k<<<1, 128, 0, stream>>>(aux, nb);
  finalize_k<<<(N_NODES + 255) / 256, 256, 0, stream>>>(cnt, rowptr, aux, bcur, dinv);
  passA_k<<<NBLKA, 256, 0, stream>>>(ei, bcur, tmp);
  passB_k<<<NBKT2, 256, 0, stream>>>(tmp, rowptr, srcs);
  gemm1_mfma_k<<<(N_NODES + 63) / 64, 256, 0, stream>>>(x, W1t, dinv, h0s);
  agg1_k<<<(N_NODES * 64) / 256, 256, 0, stream>>>((const uint2*)h0s, rowptr, srcs, dinv, b1, out_h);
  gemm2_k<<<(N_NODES + 7) / 8, 256, 0, stream>>>(out_h, W2, dinv, h2b);
  agg2_k<<<(N_NODES * 64) / 256, 256, 0, stream>>>((const unsigned*)h2b, rowptr, srcs, dinv, b2, out_z);
}

// Round 5
// 232.827 us; speedup vs baseline: 1.6867x; 1.2068x over previous
//
#include <hip/hip_runtime.h>

#define N_NODES 100000
#define N_EDGES 1600000
#define IN_F 512
#define HID 64
#define N_CLS 32
#define NBKT2 391      // 256-node buckets: ceil(100000/256)
#define EBLK 8192      // edges per passA/coarse-hist block
#define NBLKA ((N_EDGES + EBLK - 1) / EBLK)   // 196

typedef __attribute__((ext_vector_type(8))) short short8;
typedef __attribute__((ext_vector_type(4))) float f32x4;

__device__ __forceinline__ unsigned short f2bf(float f) {
  unsigned int u = __float_as_uint(f);
  u += 0x7FFFu + ((u >> 16) & 1u);
  return (unsigned short)(u >> 16);
}
__device__ __forceinline__ float bf2f(unsigned int s) {
  return __uint_as_float(s << 16);
}

// ---------- coarse histogram over 391 buckets (LDS-staged) ----------
__global__ __launch_bounds__(256) void coarse_hist_k(const int* __restrict__ ei,
                                                     int* __restrict__ bcnt) {
  __shared__ int lh[NBKT2];
  int tid = threadIdx.x;
  for (int b = tid; b < NBKT2; b += 256) lh[b] = 0;
  __syncthreads();
  int e0 = blockIdx.x * EBLK;
  int e1 = min(e0 + EBLK, N_EDGES);
  for (int e = e0 + tid; e < e1; e += 256)
    atomicAdd(&lh[ei[N_EDGES + e] >> 8], 1);
  __syncthreads();
  for (int b = tid; b < NBKT2; b += 256) {
    int c = lh[b];
    if (c) atomicAdd(&bcnt[b], c);
  }
}

// ---------- single-block scan of 391 bucket counts ----------
__global__ __launch_bounds__(512) void coarse_scan_k(const int* __restrict__ bcnt,
                                                     int* __restrict__ bbase,
                                                     int* __restrict__ bcur) {
  __shared__ int sc[512];
  int tid = threadIdx.x;
  int v = (tid < NBKT2) ? bcnt[tid] : 0;
  sc[tid] = v;
  __syncthreads();
  for (int off = 1; off < 512; off <<= 1) {
    int t = (tid >= off) ? sc[tid - off] : 0;
    __syncthreads();
    sc[tid] += t;
    __syncthreads();
  }
  int incl = sc[tid];
  int excl = incl - v;
  if (tid < NBKT2) { bbase[tid] = excl; bcur[tid] = excl; }
  if (tid == NBKT2 - 1) bbase[NBKT2] = incl;   // == N_EDGES
}

// ---------- pass A: block-private run reservation into 256-node buckets ----------
__global__ __launch_bounds__(256) void passA_k(const int* __restrict__ ei,
                                               int* __restrict__ bcur,
                                               unsigned* __restrict__ tmp) {
  __shared__ int lhist[NBKT2];
  __shared__ int gcur[NBKT2];
  int tid = threadIdx.x;
  int e0 = blockIdx.x * EBLK;
  int e1 = min(e0 + EBLK, N_EDGES);
  for (int b = tid; b < NBKT2; b += 256) lhist[b] = 0;
  __syncthreads();
  for (int e = e0 + tid; e < e1; e += 256) {
    int d = ei[N_EDGES + e];
    atomicAdd(&lhist[d >> 8], 1);
  }
  __syncthreads();
  for (int b = tid; b < NBKT2; b += 256) {
    int c = lhist[b];
    gcur[b] = c ? atomicAdd(&bcur[b], c) : 0;
  }
  __syncthreads();
  for (int e = e0 + tid; e < e1; e += 256) {
    int s = ei[e], d = ei[N_EDGES + e];
    int p = atomicAdd(&gcur[d >> 8], 1);
    tmp[p] = ((unsigned)s << 8) | (unsigned)(d & 255);
  }
}

// ---------- pass B: per-bucket node hist + scan + rowptr/dinv + exact placement ----------
__global__ __launch_bounds__(256) void passB_k(const unsigned* __restrict__ tmp,
                                               const int* __restrict__ bbase,
                                               int* __restrict__ rowptr,
                                               float* __restrict__ dinv,
                                               int* __restrict__ srcs) {
  __shared__ int sc[256];
  __shared__ int cur[256];
  int b = blockIdx.x, tid = threadIdx.x;
  int n0 = b << 8;
  int n1 = min(n0 + 256, N_NODES);
  int base = bbase[b], end = bbase[b + 1];
  sc[tid] = 0;
  __syncthreads();
  for (int i = base + tid; i < end; i += 256)
    atomicAdd(&sc[tmp[i] & 255u], 1);
  __syncthreads();
  int myc = sc[tid];
  // Hillis-Steele inclusive scan over 256
  for (int off = 1; off < 256; off <<= 1) {
    int t = (tid >= off) ? sc[tid - off] : 0;
    __syncthreads();
    sc[tid] += t;
    __syncthreads();
  }
  int incl = sc[tid];
  int excl = incl - myc;
  if (n0 + tid < n1) {
    rowptr[n0 + tid + 1] = base + incl;
    dinv[n0 + tid] = rsqrtf((float)(myc + 1));
  }
  if (b == 0 && tid == 0) rowptr[0] = 0;
  cur[tid] = base + excl;
  __syncthreads();
  for (int i = base + tid; i < end; i += 256) {
    unsigned v = tmp[i];
    int p = atomicAdd(&cur[v & 255u], 1);
    srcs[p] = (int)(v >> 8);
  }
}

// ---------- W1 transpose to bf16 ----------
__global__ __launch_bounds__(256) void w1t_k(const float* __restrict__ W1,
                                             unsigned short* __restrict__ W1t) {
  int i = blockIdx.x * 256 + threadIdx.x;
  if (i < IN_F * HID) {
    int n = i >> 9, k = i & 511;
    W1t[i] = f2bf(W1[(size_t)k * HID + n]);
  }
}

// ---------- GEMM1 (MFMA bf16): h0s = dinv * (x @ W1), bf16 ----------
__global__ __launch_bounds__(256) void gemm1_mfma_k(const float* __restrict__ x,
                                                    const unsigned short* __restrict__ W1t,
                                                    const float* __restrict__ dinv,
                                                    unsigned short* __restrict__ h0s) {
  __shared__ __align__(16) char As[64 * 128];
  __shared__ __align__(16) char Ws[64 * 128];
  int tid = threadIdx.x;
  int wave = tid >> 6, lane = tid & 63;
  int row0 = blockIdx.x * 64;
  f32x4 acc[4] = {{0.f,0.f,0.f,0.f},{0.f,0.f,0.f,0.f},{0.f,0.f,0.f,0.f},{0.f,0.f,0.f,0.f}};

  int l15 = lane & 15, lhi = lane >> 4;
  int rA = (wave << 4) + l15;

  for (int k0 = 0; k0 < IN_F; k0 += 64) {
    #pragma unroll
    for (int i = 0; i < 4; ++i) {
      int f = tid + i * 256;
      int r = f >> 4, c4 = (f & 15) << 2;
      float4 v = make_float4(0.f, 0.f, 0.f, 0.f);
      int gr = row0 + r;
      if (gr < N_NODES) v = *(const float4*)(x + (size_t)gr * IN_F + k0 + c4);
      ushort4 u;
      u.x = f2bf(v.x); u.y = f2bf(v.y); u.z = f2bf(v.z); u.w = f2bf(v.w);
      int byte = r * 128 + (c4 << 1);
      byte ^= (r & 7) << 4;
      *(ushort4*)(As + byte) = u;
    }
    #pragma unroll
    for (int i = 0; i < 2; ++i) {
      int f = tid + i * 256;
      int n = f >> 3, k8 = (f & 7) << 3;
      uint4 v = *(const uint4*)(W1t + (size_t)n * IN_F + k0 + k8);
      int byte = n * 128 + (k8 << 1);
      byte ^= (n & 7) << 4;
      *(uint4*)(Ws + byte) = v;
    }
    __syncthreads();
    #pragma unroll
    for (int ks = 0; ks < 64; ks += 32) {
      int kk = ks + (lhi << 3);
      int ba = rA * 128 + (kk << 1); ba ^= (rA & 7) << 4;
      short8 a = *(const short8*)(As + ba);
      #pragma unroll
      for (int j = 0; j < 4; ++j) {
        int nB = (j << 4) + l15;
        int bb = nB * 128 + (kk << 1); bb ^= (nB & 7) << 4;
        short8 bv = *(const short8*)(Ws + bb);
        acc[j] = __builtin_amdgcn_mfma_f32_16x16x32_bf16(a, bv, acc[j], 0, 0, 0);
      }
    }
    __syncthreads();
  }
  int rbase = row0 + (wave << 4) + (lhi << 2);
  #pragma unroll
  for (int r = 0; r < 4; ++r) {
    int gr = rbase + r;
    if (gr < N_NODES) {
      float dn = dinv[gr];
      #pragma unroll
      for (int j = 0; j < 4; ++j)
        h0s[(size_t)gr * HID + (j << 4) + l15] = f2bf(dn * acc[j][r]);
    }
  }
}

// ---------- agg1: one wave/node, 8-way edge split, 8 feats/lane (uint4) ----------
__global__ __launch_bounds__(256) void agg1_k(const uint4* __restrict__ h0q,
                                              const int* __restrict__ rowptr,
                                              const int* __restrict__ srcs,
                                              const float* __restrict__ dinv,
                                              const float* __restrict__ b1,
                                              float* __restrict__ out) {
  int idx = blockIdx.x * 256 + threadIdx.x;
  int node = idx >> 6;
  if (node >= N_NODES) return;
  int lane = threadIdx.x & 63;
  int fl = lane & 7, g = lane >> 3;
  int p0 = rowptr[node], p1 = rowptr[node + 1];
  int c = p1 - p0;
  int ps = p0 + ((c * g) >> 3);
  int pe = p0 + ((c * (g + 1)) >> 3);
  float a[8] = {0.f,0.f,0.f,0.f,0.f,0.f,0.f,0.f};
  if (g == 0) {
    uint4 u = h0q[(size_t)node * 8 + fl];     // self (pre-scaled)
    a[0] = bf2f(u.x & 0xffffu); a[1] = bf2f(u.x >> 16);
    a[2] = bf2f(u.y & 0xffffu); a[3] = bf2f(u.y >> 16);
    a[4] = bf2f(u.z & 0xffffu); a[5] = bf2f(u.z >> 16);
    a[6] = bf2f(u.w & 0xffffu); a[7] = bf2f(u.w >> 16);
  }
  int p = ps;
  for (; p + 2 <= pe; p += 2) {
    int s0 = srcs[p], s1 = srcs[p + 1];
    uint4 u0 = h0q[(size_t)s0 * 8 + fl];
    uint4 u1 = h0q[(size_t)s1 * 8 + fl];
    a[0] += bf2f(u0.x & 0xffffu) + bf2f(u1.x & 0xffffu);
    a[1] += bf2f(u0.x >> 16)     + bf2f(u1.x >> 16);
    a[2] += bf2f(u0.y & 0xffffu) + bf2f(u1.y & 0xffffu);
    a[3] += bf2f(u0.y >> 16)     + bf2f(u1.y >> 16);
    a[4] += bf2f(u0.z & 0xffffu) + bf2f(u1.z & 0xffffu);
    a[5] += bf2f(u0.z >> 16)     + bf2f(u1.z >> 16);
    a[6] += bf2f(u0.w & 0xffffu) + bf2f(u1.w & 0xffffu);
    a[7] += bf2f(u0.w >> 16)     + bf2f(u1.w >> 16);
  }
  if (p < pe) {
    uint4 u = h0q[(size_t)srcs[p] * 8 + fl];
    a[0] += bf2f(u.x & 0xffffu); a[1] += bf2f(u.x >> 16);
    a[2] += bf2f(u.y & 0xffffu); a[3] += bf2f(u.y >> 16);
    a[4] += bf2f(u.z & 0xffffu); a[5] += bf2f(u.z >> 16);
    a[6] += bf2f(u.w & 0xffffu); a[7] += bf2f(u.w >> 16);
  }
  #pragma unroll
  for (int off = 8; off < 64; off <<= 1) {
    #pragma unroll
    for (int i = 0; i < 8; ++i) a[i] += __shfl_xor(a[i], off);
  }
  if (g == 0) {
    float dn = dinv[node];
    float4 bA = *(const float4*)(b1 + fl * 8);
    float4 bB = *(const float4*)(b1 + fl * 8 + 4);
    float4 s0, s1;
    s0.x = fmaxf(dn * a[0] + bA.x, 0.f); s0.y = fmaxf(dn * a[1] + bA.y, 0.f);
    s0.z = fmaxf(dn * a[2] + bA.z, 0.f); s0.w = fmaxf(dn * a[3] + bA.w, 0.f);
    s1.x = fmaxf(dn * a[4] + bB.x, 0.f); s1.y = fmaxf(dn * a[5] + bB.y, 0.f);
    s1.z = fmaxf(dn * a[6] + bB.z, 0.f); s1.w = fmaxf(dn * a[7] + bB.w, 0.f);
    *(float4*)(out + (size_t)node * HID + fl * 8) = s0;
    *(float4*)(out + (size_t)node * HID + fl * 8 + 4) = s1;
  }
}

// ---------- GEMM2: h2b = bf16(dinv * (h @ W2)), 32 nodes/block ----------
__global__ __launch_bounds__(256) void gemm2_k(const float* __restrict__ h,
                                               const float* __restrict__ W2,
                                               const float* __restrict__ dinv,
                                               unsigned short* __restrict__ h2b) {
  __shared__ float w2s[HID * N_CLS];
  __shared__ float hs[32][HID];
  int tid = threadIdx.x;
  for (int i = tid; i < HID * N_CLS; i += 256) w2s[i] = W2[i];
  int node0 = blockIdx.x * 32;
  for (int i = tid; i < 32 * HID / 4; i += 256) {   // 512 float4 loads
    int r = i >> 4, c4 = (i & 15) << 2;
    int g = node0 + r;
    float4 v = make_float4(0.f, 0.f, 0.f, 0.f);
    if (g < N_NODES) v = *(const float4*)(h + (size_t)g * HID + c4);
    *(float4*)&hs[r][c4] = v;
  }
  __syncthreads();
  int cls = tid & 31, nl = tid >> 5;   // nl in 0..7, 4 nodes each
  float acc[4] = {0.f, 0.f, 0.f, 0.f};
  #pragma unroll
  for (int k = 0; k < HID; ++k) {
    float w = w2s[k * N_CLS + cls];
    #pragma unroll
    for (int j = 0; j < 4; ++j) acc[j] += hs[nl * 4 + j][k] * w;
  }
  #pragma unroll
  for (int j = 0; j < 4; ++j) {
    int g = node0 + nl * 4 + j;
    if (g < N_NODES) h2b[(size_t)g * N_CLS + cls] = f2bf(dinv[g] * acc[j]);
  }
}

// ---------- agg2: one wave/node, 8-way edge split, 4 feats/lane (uint2) ----------
__global__ __launch_bounds__(256) void agg2_k(const uint2* __restrict__ h2u,
                                              const int* __restrict__ rowptr,
                                              const int* __restrict__ srcs,
                                              const float* __restrict__ dinv,
                                              const float* __restrict__ b2,
                                              float* __restrict__ out) {
  int idx = blockIdx.x * 256 + threadIdx.x;
  int node = idx >> 6;
  if (node >= N_NODES) return;
  int lane = threadIdx.x & 63;
  int fl = lane & 7, g = lane >> 3;
  int p0 = rowptr[node], p1 = rowptr[node + 1];
  int c = p1 - p0;
  int ps = p0 + ((c * g) >> 3);
  int pe = p0 + ((c * (g + 1)) >> 3);
  float a0 = 0.f, a1 = 0.f, a2 = 0.f, a3 = 0.f;
  if (g == 0) {
    uint2 u = h2u[(size_t)node * 8 + fl];
    a0 = bf2f(u.x & 0xffffu); a1 = bf2f(u.x >> 16);
    a2 = bf2f(u.y & 0xffffu); a3 = bf2f(u.y >> 16);
  }
  int p = ps;
  for (; p + 2 <= pe; p += 2) {
    int s0 = srcs[p], s1 = srcs[p + 1];
    uint2 u0 = h2u[(size_t)s0 * 8 + fl];
    uint2 u1 = h2u[(size_t)s1 * 8 + fl];
    a0 += bf2f(u0.x & 0xffffu) + bf2f(u1.x & 0xffffu);
    a1 += bf2f(u0.x >> 16)     + bf2f(u1.x >> 16);
    a2 += bf2f(u0.y & 0xffffu) + bf2f(u1.y & 0xffffu);
    a3 += bf2f(u0.y >> 16)     + bf2f(u1.y >> 16);
  }
  if (p < pe) {
    uint2 u = h2u[(size_t)srcs[p] * 8 + fl];
    a0 += bf2f(u.x & 0xffffu); a1 += bf2f(u.x >> 16);
    a2 += bf2f(u.y & 0xffffu); a3 += bf2f(u.y >> 16);
  }
  #pragma unroll
  for (int off = 8; off < 64; off <<= 1) {
    a0 += __shfl_xor(a0, off); a1 += __shfl_xor(a1, off);
    a2 += __shfl_xor(a2, off); a3 += __shfl_xor(a3, off);
  }
  if (g == 0) {
    float dn = dinv[node];
    float4 bv = *(const float4*)(b2 + fl * 4);
    float4 st;
    st.x = dn * a0 + bv.x; st.y = dn * a1 + bv.y;
    st.z = dn * a2 + bv.z; st.w = dn * a3 + bv.w;
    *(float4*)(out + (size_t)node * N_CLS + fl * 4) = st;
  }
}

extern "C" void kernel_launch(void* const* d_in, const int* in_sizes, int n_in,
                              void* d_out, int out_size, void* d_ws, size_t ws_size,
                              hipStream_t stream) {
  const float* x  = (const float*)d_in[0];
  const int*   ei = (const int*)d_in[1];
  const float* W1 = (const float*)d_in[2];
  const float* b1 = (const float*)d_in[3];
  const float* W2 = (const float*)d_in[4];
  const float* b2 = (const float*)d_in[5];
  float* out_h = (float*)d_out;
  float* out_z = out_h + (size_t)N_NODES * HID;

  char* ws = (char*)d_ws;
  int* bcnt           = (int*)(ws + 0);                       // 1.6 KB
  int* bbase          = (int*)(ws + (4 << 10));               // 1.6 KB
  int* bcur           = (int*)(ws + (8 << 10));               // 1.6 KB
  int* rowptr         = (int*)(ws + (16 << 10));              // 400 KB + 4
  float* dinv         = (float*)(ws + (528 << 10));           // 400 KB
  unsigned short* W1t = (unsigned short*)(ws + (944 << 10));  // 64 KB
  unsigned* tmp       = (unsigned*)(ws + (1024 << 10));       // 6.4 MB
  int* srcs           = (int*)(ws + (8ull << 20));            // 6.4 MB
  unsigned short* h0s = (unsigned short*)(ws + (15ull << 20));// 12.8 MB
  unsigned short* h2b = (unsigned short*)(ws + (28ull << 20));// 6.4 MB

  hipMemsetAsync(bcnt, 0, NBKT2 * sizeof(int), stream);
  w1t_k<<<(IN_F * HID + 255) / 256, 256, 0, stream>>>(W1, W1t);
  coarse_hist_k<<<NBLKA, 256, 0, stream>>>(ei, bcnt);
  coarse_scan_k<<<1, 512, 0, stream>>>(bcnt, bbase, bcur);
  passA_k<<<NBLKA, 256, 0, stream>>>(ei, bcur, tmp);
  passB_k<<<NBKT2, 256, 0, stream>>>(tmp, bbase, rowptr, dinv, srcs);
  gemm1_mfma_k<<<(N_NODES + 63) / 64, 256, 0, stream>>>(x, W1t, dinv, h0s);
  agg1_k<<<(N_NODES * 64) / 256, 256, 0, stream>>>((const uint4*)h0s, rowptr, srcs, dinv, b1, out_h);
  gemm2_k<<<(N_NODES + 31) / 32, 256, 0, stream>>>(out_h, W2, dinv, h2b);
  agg2_k<<<(N_NODES * 64) / 256, 256, 0, stream>>>((const uint2*)h2b, rowptr, srcs, dinv, b2, out_z);
}